// Round 1
// baseline (716.108 us; speedup 1.0000x reference)
//
#include <hip/hip_runtime.h>

// BRNN integrate one-hot: h_{t} = clip(h_{t-1} @ fsa[tok_t], -10, 10)
// B=64 L=512 S=128 V=10000. One block per batch row, 512 threads (8 waves).
// Register double-buffer prefetch of the next 64KB transition matrix.

constexpr int S_DIM = 128;
constexpr int L_DIM = 512;
constexpr int B_DIM = 64;
constexpr int NT    = 512;        // threads per block
constexpr int RG    = NT / 32;    // 16 row-groups (32 threads each cover 128 cols via float4)
constexpr int RPG   = S_DIM / RG; // 8 rows per group

__global__ __launch_bounds__(NT, 2)
void brnn_scan(const int* __restrict__ tokens,
               const float* __restrict__ fsa,
               float* __restrict__ out) {
    const int b    = blockIdx.x;
    const int tid  = threadIdx.x;
    const int cgrp = tid & 31;   // column group: cols 4*cgrp .. 4*cgrp+3
    const int rgrp = tid >> 5;   // row group:   rows rgrp*RPG .. +RPG-1

    __shared__ float  h[S_DIM];
    __shared__ float4 part4[RG][32];   // float4 writes -> conflict-free pattern

    if (tid < S_DIM) h[tid] = (tid == 0) ? 1.0f : 0.0f;

    const int* btok = tokens + b * L_DIM;
    float* bout = out + (size_t)b * (L_DIM * S_DIM);

    // prefetch matrix for t = 0
    float4 cur[RPG];
    {
        const float* M = fsa + (size_t)btok[0] * (S_DIM * S_DIM);
        #pragma unroll
        for (int i = 0; i < RPG; ++i)
            cur[i] = *reinterpret_cast<const float4*>(M + (rgrp * RPG + i) * S_DIM + cgrp * 4);
    }
    __syncthreads();

    for (int t = 0; t < L_DIM; ++t) {
        // issue next-step loads early: address depends only on tokens, not on h
        const int tn = (t + 1 < L_DIM) ? (t + 1) : t;
        float4 nxt[RPG];
        {
            const float* M = fsa + (size_t)btok[tn] * (S_DIM * S_DIM);
            #pragma unroll
            for (int i = 0; i < RPG; ++i)
                nxt[i] = *reinterpret_cast<const float4*>(M + (rgrp * RPG + i) * S_DIM + cgrp * 4);
        }

        // partial mat-vec for this thread's row-group / column-group
        float4 acc = make_float4(0.f, 0.f, 0.f, 0.f);
        #pragma unroll
        for (int i = 0; i < RPG; ++i) {
            const float hs = h[rgrp * RPG + i];
            acc.x += hs * cur[i].x;
            acc.y += hs * cur[i].y;
            acc.z += hs * cur[i].z;
            acc.w += hs * cur[i].w;
        }

        __syncthreads();                 // all reads of h / part4 from prev iter done
        part4[rgrp][cgrp] = acc;
        __syncthreads();

        if (tid < S_DIM) {
            const float* pf = reinterpret_cast<const float*>(part4);
            float v = 0.f;
            #pragma unroll
            for (int g = 0; g < RG; ++g) v += pf[g * S_DIM + tid];
            v = fminf(fmaxf(v, -10.0f), 10.0f);
            bout[t * S_DIM + tid] = v;
            h[tid] = v;
        }
        __syncthreads();

        #pragma unroll
        for (int i = 0; i < RPG; ++i) cur[i] = nxt[i];
    }
}

extern "C" void kernel_launch(void* const* d_in, const int* in_sizes, int n_in,
                              void* d_out, int out_size, void* d_ws, size_t ws_size,
                              hipStream_t stream) {
    const int*   tokens = (const int*)d_in[0];     // [B, L] token ids
    // d_in[1] = lengths — unused by the reference computation
    const float* fsa    = (const float*)d_in[2];   // [V, S, S] f32
    float*       out    = (float*)d_out;           // [B, L, S] f32

    brnn_scan<<<B_DIM, NT, 0, stream>>>(tokens, fsa, out);
}

// Round 2
// 137.041 us; speedup vs baseline: 5.2255x; 5.2255x over previous
//
#include <hip/hip_runtime.h>

// BRNN integrate one-hot: h_t = clip(h_{t-1} @ fsa[tok_t], -10, 10)
// B=64 L=512 S=128 V=10000, fsa ~ U[0,1).
//
// Structure: clip(+10) is an absorbing state. h2 saturates to all-10s, and it
// stays all-10s for every subsequent token whose matrix has min column-sum >= 1.
// We CERTIFY this on-device (exact for any input):
//   k1 colsum_certify : per-vocab min colsum >= 1          (reads fsa once, 655 MB)
//   k2 head_and_check : exact t=0,1 per batch + certificate check
//   k3 fill_saturated : out[b,2:,:] = 10.0 for certified batches
//   k4 fallback_scan  : full exact scan, early-exit per batch unless certificate failed

constexpr int S_DIM = 128;
constexpr int L_DIM = 512;
constexpr int B_DIM = 64;
constexpr int V_DIM = 10000;
constexpr int NT    = 512;        // fallback threads/block
constexpr int RG    = NT / 32;
constexpr int RPG   = S_DIM / RG;

// ---------------- k1: per-vocab certification ----------------
__global__ __launch_bounds__(256)
void colsum_certify(const float* __restrict__ fsa, int* __restrict__ minok) {
    const int v   = blockIdx.x;
    const int tid = threadIdx.x;
    const int c4  = tid & 31;    // columns 4*c4 .. 4*c4+3
    const int rg  = tid >> 5;    // 8 row-groups of 16 rows

    const float* M = fsa + (size_t)v * (S_DIM * S_DIM);
    float4 acc = make_float4(0.f, 0.f, 0.f, 0.f);
    #pragma unroll
    for (int i = 0; i < 16; ++i) {
        float4 m = *reinterpret_cast<const float4*>(M + (rg * 16 + i) * S_DIM + c4 * 4);
        acc.x += m.x; acc.y += m.y; acc.z += m.z; acc.w += m.w;
    }

    __shared__ float4 part[8][32];
    __shared__ int ok;
    part[rg][c4] = acc;
    if (tid == 0) ok = 1;
    __syncthreads();

    if (tid < 32) {
        float4 s = part[0][tid];
        #pragma unroll
        for (int g = 1; g < 8; ++g) {
            float4 p = part[g][tid];
            s.x += p.x; s.y += p.y; s.z += p.z; s.w += p.w;
        }
        float mn = fminf(fminf(s.x, s.y), fminf(s.z, s.w));
        if (mn < 1.0f) ok = 0;           // only-zero writes: benign race
    }
    __syncthreads();
    if (tid == 0) minok[v] = ok;
}

// ---------------- k2: exact head (t=0,1) + saturation certificate ----------------
__global__ __launch_bounds__(128)
void head_and_check(const int* __restrict__ tokens, const float* __restrict__ fsa,
                    const int* __restrict__ minok, int* __restrict__ need_fb,
                    float* __restrict__ out) {
    const int b = blockIdx.x;
    const int j = threadIdx.x;            // one thread per state
    const int* btok = tokens + b * L_DIM;
    float* bout = out + (size_t)b * (L_DIM * S_DIM);

    __shared__ float h1[S_DIM];
    __shared__ int sat;
    if (j == 0) sat = 1;

    // t = 0: h1 = clip(row 0 of M[tok0])
    {
        const float* M0 = fsa + (size_t)btok[0] * (S_DIM * S_DIM);
        float v = fminf(fmaxf(M0[j], -10.f), 10.f);
        h1[j] = v;
        bout[j] = v;
    }
    __syncthreads();

    // t = 1: h2[j] = clip(sum_s h1[s] * M1[s][j])
    {
        const float* M1 = fsa + (size_t)btok[1] * (S_DIM * S_DIM);
        float acc = 0.f;
        #pragma unroll 8
        for (int s = 0; s < S_DIM; ++s)
            acc += h1[s] * M1[s * S_DIM + j];
        bout[S_DIM + j] = fminf(fmaxf(acc, -10.f), 10.f);
        if (!(acc >= 10.0f)) sat = 0;    // saturation must be exact in every lane
    }

    // every token from t=2 on must be certified (min colsum >= 1)
    for (int t = 2 + j; t < L_DIM; t += 128)
        if (!minok[btok[t]]) sat = 0;

    __syncthreads();
    if (j == 0) need_fb[b] = !sat;
}

// ---------------- k3: constant fill for certified batches ----------------
__global__ __launch_bounds__(256)
void fill_saturated(const int* __restrict__ need_fb, float* __restrict__ out) {
    const int b = blockIdx.x;
    if (need_fb[b]) return;
    const int g = blockIdx.y;                       // 8 slices
    float4* p = reinterpret_cast<float4*>(out + (size_t)b * (L_DIM * S_DIM) + 2 * S_DIM);
    const int n4 = (L_DIM - 2) * S_DIM / 4;         // 16320
    const float4 ten = make_float4(10.f, 10.f, 10.f, 10.f);
    for (int i = g * 256 + threadIdx.x; i < n4; i += 8 * 256)
        p[i] = ten;
}

// ---------------- k4: exact fallback scan (round-1 kernel, gated) ----------------
__global__ __launch_bounds__(NT, 2)
void fallback_scan(const int* __restrict__ tokens, const float* __restrict__ fsa,
                   const int* __restrict__ need_fb, float* __restrict__ out) {
    const int b = blockIdx.x;
    if (!need_fb[b]) return;              // certificate held: nothing to do

    const int tid  = threadIdx.x;
    const int cgrp = tid & 31;
    const int rgrp = tid >> 5;

    __shared__ float  h[S_DIM];
    __shared__ float4 part4[RG][32];

    if (tid < S_DIM) h[tid] = (tid == 0) ? 1.0f : 0.0f;

    const int* btok = tokens + b * L_DIM;
    float* bout = out + (size_t)b * (L_DIM * S_DIM);

    float4 cur[RPG];
    {
        const float* M = fsa + (size_t)btok[0] * (S_DIM * S_DIM);
        #pragma unroll
        for (int i = 0; i < RPG; ++i)
            cur[i] = *reinterpret_cast<const float4*>(M + (rgrp * RPG + i) * S_DIM + cgrp * 4);
    }
    __syncthreads();

    for (int t = 0; t < L_DIM; ++t) {
        const int tn = (t + 1 < L_DIM) ? (t + 1) : t;
        float4 nxt[RPG];
        {
            const float* M = fsa + (size_t)btok[tn] * (S_DIM * S_DIM);
            #pragma unroll
            for (int i = 0; i < RPG; ++i)
                nxt[i] = *reinterpret_cast<const float4*>(M + (rgrp * RPG + i) * S_DIM + cgrp * 4);
        }

        float4 acc = make_float4(0.f, 0.f, 0.f, 0.f);
        #pragma unroll
        for (int i = 0; i < RPG; ++i) {
            const float hs = h[rgrp * RPG + i];
            acc.x += hs * cur[i].x;
            acc.y += hs * cur[i].y;
            acc.z += hs * cur[i].z;
            acc.w += hs * cur[i].w;
        }

        __syncthreads();
        part4[rgrp][cgrp] = acc;
        __syncthreads();

        if (tid < S_DIM) {
            const float* pf = reinterpret_cast<const float*>(part4);
            float v = 0.f;
            #pragma unroll
            for (int g = 0; g < RG; ++g) v += pf[g * S_DIM + tid];
            v = fminf(fmaxf(v, -10.0f), 10.0f);
            bout[t * S_DIM + tid] = v;
            h[tid] = v;
        }
        __syncthreads();

        #pragma unroll
        for (int i = 0; i < RPG; ++i) cur[i] = nxt[i];
    }
}

extern "C" void kernel_launch(void* const* d_in, const int* in_sizes, int n_in,
                              void* d_out, int out_size, void* d_ws, size_t ws_size,
                              hipStream_t stream) {
    const int*   tokens = (const int*)d_in[0];     // [B, L]
    // d_in[1] = lengths — unused by the reference computation
    const float* fsa    = (const float*)d_in[2];   // [V, S, S] f32
    float*       out    = (float*)d_out;           // [B, L, S] f32

    int* minok   = (int*)d_ws;                     // [V_DIM]
    int* need_fb = minok + V_DIM;                  // [B_DIM]

    colsum_certify<<<V_DIM, 256, 0, stream>>>(fsa, minok);
    head_and_check<<<B_DIM, 128, 0, stream>>>(tokens, fsa, minok, need_fb, out);
    fill_saturated<<<dim3(B_DIM, 8), 256, 0, stream>>>(need_fb, out);
    fallback_scan<<<B_DIM, NT, 0, stream>>>(tokens, fsa, need_fb, out);
}

// Round 3
// 26.479 us; speedup vs baseline: 27.0446x; 5.1755x over previous
//
#include <hip/hip_runtime.h>

// BRNN integrate one-hot: h_t = clip(h_{t-1} @ fsa[tok_t], -10, 10)
// B=64 L=512 S=128 V=10000, fsa = U[0,1) (non-negative by problem spec).
//
// clip(+10) is absorbing: h2 saturates to all-10s; it stays there for every
// token whose matrix has min column-sum >= 1. Since fsa entries are >= 0,
// a PARTIAL column sum over rows 0..15 >= 1 is a sound certificate
// (lower-bounds the full sum). Reads 82 MB instead of 655 MB.
//   k1 certify_and_fill : partial-colsum cert + unconditional 10.0-fill of out[:,2:,:]
//   k2 head_and_check   : exact t=0,1 per batch + per-batch certificate check
//   k3 fallback_scan    : full exact scan per batch, gated on certificate failure

constexpr int S_DIM  = 128;
constexpr int L_DIM  = 512;
constexpr int B_DIM  = 64;
constexpr int V_DIM  = 10000;
constexpr int NT     = 512;        // fallback threads/block
constexpr int RG     = NT / 32;
constexpr int RPG    = S_DIM / RG;

// ---------------- k1: partial-colsum certificate + output fill ----------------
__global__ __launch_bounds__(256)
void certify_and_fill(const float* __restrict__ fsa, int* __restrict__ minok,
                      float* __restrict__ out) {
    const int v   = blockIdx.x;
    const int tid = threadIdx.x;
    const int c4  = tid & 31;    // columns 4*c4 .. 4*c4+3
    const int rg  = tid >> 5;    // 0..7; this thread covers rows rg and rg+8

    const float* M = fsa + (size_t)v * (S_DIM * S_DIM);
    float4 a = *reinterpret_cast<const float4*>(M + rg       * S_DIM + c4 * 4);
    float4 b = *reinterpret_cast<const float4*>(M + (rg + 8) * S_DIM + c4 * 4);
    float4 acc = make_float4(a.x + b.x, a.y + b.y, a.z + b.z, a.w + b.w);

    // unconditional saturated fill: out[:, 2:, :] = 10.0 (one float4/thread)
    {
        const int per_b = (L_DIM - 2) * S_DIM / 4;            // 16320
        const int i = blockIdx.x * 256 + tid;
        if (i < per_b * B_DIM) {
            const int bb = i / per_b;
            const int r  = i - bb * per_b;
            float4* p = reinterpret_cast<float4*>(out + (size_t)bb * (L_DIM * S_DIM) + 2 * S_DIM);
            p[r] = make_float4(10.f, 10.f, 10.f, 10.f);
        }
    }

    __shared__ float4 part[8][32];
    __shared__ int ok;
    if (tid == 0) ok = 1;
    part[rg][c4] = acc;
    __syncthreads();

    if (tid < 32) {
        float4 s = part[0][tid];
        #pragma unroll
        for (int g = 1; g < 8; ++g) {
            float4 p = part[g][tid];
            s.x += p.x; s.y += p.y; s.z += p.z; s.w += p.w;
        }
        float mn = fminf(fminf(s.x, s.y), fminf(s.z, s.w));
        if (mn < 1.0f) ok = 0;            // only-zero writes: benign race
    }
    __syncthreads();
    if (tid == 0) minok[v] = ok;
}

// ---------------- k2: exact head (t=0,1) + per-batch certificate ----------------
__global__ __launch_bounds__(512)
void head_and_check(const int* __restrict__ tokens, const float* __restrict__ fsa,
                    const int* __restrict__ minok, int* __restrict__ need_fb,
                    float* __restrict__ out) {
    const int b   = blockIdx.x;
    const int tid = threadIdx.x;
    const int j   = tid & 127;            // state/column
    const int q   = tid >> 7;             // row quarter 0..3
    const int* btok = tokens + b * L_DIM;
    float* bout = out + (size_t)b * (L_DIM * S_DIM);

    __shared__ float h1[S_DIM];
    __shared__ float part[4][S_DIM];
    __shared__ int sat;
    if (tid == 0) sat = 1;

    const float* M0 = fsa + (size_t)btok[0] * (S_DIM * S_DIM);
    const float* M1 = fsa + (size_t)btok[1] * (S_DIM * S_DIM);

    // t = 0: h1 = clip(row 0 of M0)
    if (q == 0) {
        float v = fminf(fmaxf(M0[j], -10.f), 10.f);
        h1[j] = v;
        bout[j] = v;
    }
    __syncthreads();

    // t = 1: 4-way row-split matvec
    float acc = 0.f;
    {
        const int s0 = q * 32;
        #pragma unroll 8
        for (int s = s0; s < s0 + 32; ++s)
            acc += h1[s] * M1[s * S_DIM + j];
    }
    part[q][j] = acc;

    // certificate: every token at t>=2 must have partial colsum >= 1
    for (int t = 2 + tid; t < L_DIM; t += 512)
        if (!minok[btok[t]]) sat = 0;
    __syncthreads();

    if (q == 0) {
        float v = part[0][j] + part[1][j] + part[2][j] + part[3][j];
        if (!(v >= 10.0f)) sat = 0;       // saturation must hold in every lane
        bout[S_DIM + j] = fminf(fmaxf(v, -10.f), 10.f);
    }
    __syncthreads();
    if (tid == 0) need_fb[b] = !sat;
}

// ---------------- k3: exact fallback scan (gated) ----------------
__global__ __launch_bounds__(NT, 2)
void fallback_scan(const int* __restrict__ tokens, const float* __restrict__ fsa,
                   const int* __restrict__ need_fb, float* __restrict__ out) {
    const int b = blockIdx.x;
    if (!need_fb[b]) return;              // certificate held: nothing to do

    const int tid  = threadIdx.x;
    const int cgrp = tid & 31;
    const int rgrp = tid >> 5;

    __shared__ float  h[S_DIM];
    __shared__ float4 part4[RG][32];

    if (tid < S_DIM) h[tid] = (tid == 0) ? 1.0f : 0.0f;

    const int* btok = tokens + b * L_DIM;
    float* bout = out + (size_t)b * (L_DIM * S_DIM);

    float4 cur[RPG];
    {
        const float* M = fsa + (size_t)btok[0] * (S_DIM * S_DIM);
        #pragma unroll
        for (int i = 0; i < RPG; ++i)
            cur[i] = *reinterpret_cast<const float4*>(M + (rgrp * RPG + i) * S_DIM + cgrp * 4);
    }
    __syncthreads();

    for (int t = 0; t < L_DIM; ++t) {
        const int tn = (t + 1 < L_DIM) ? (t + 1) : t;
        float4 nxt[RPG];
        {
            const float* M = fsa + (size_t)btok[tn] * (S_DIM * S_DIM);
            #pragma unroll
            for (int i = 0; i < RPG; ++i)
                nxt[i] = *reinterpret_cast<const float4*>(M + (rgrp * RPG + i) * S_DIM + cgrp * 4);
        }

        float4 acc = make_float4(0.f, 0.f, 0.f, 0.f);
        #pragma unroll
        for (int i = 0; i < RPG; ++i) {
            const float hs = h[rgrp * RPG + i];
            acc.x += hs * cur[i].x;
            acc.y += hs * cur[i].y;
            acc.z += hs * cur[i].z;
            acc.w += hs * cur[i].w;
        }

        __syncthreads();
        part4[rgrp][cgrp] = acc;
        __syncthreads();

        if (tid < S_DIM) {
            const float* pf = reinterpret_cast<const float*>(part4);
            float v = 0.f;
            #pragma unroll
            for (int g = 0; g < RG; ++g) v += pf[g * S_DIM + tid];
            v = fminf(fmaxf(v, -10.0f), 10.0f);
            bout[t * S_DIM + tid] = v;
            h[tid] = v;
        }
        __syncthreads();

        #pragma unroll
        for (int i = 0; i < RPG; ++i) cur[i] = nxt[i];
    }
}

extern "C" void kernel_launch(void* const* d_in, const int* in_sizes, int n_in,
                              void* d_out, int out_size, void* d_ws, size_t ws_size,
                              hipStream_t stream) {
    const int*   tokens = (const int*)d_in[0];     // [B, L]
    // d_in[1] = lengths — unused by the reference computation
    const float* fsa    = (const float*)d_in[2];   // [V, S, S] f32
    float*       out    = (float*)d_out;           // [B, L, S] f32

    int* minok   = (int*)d_ws;                     // [V_DIM]
    int* need_fb = minok + V_DIM;                  // [B_DIM]

    certify_and_fill<<<V_DIM, 256, 0, stream>>>(fsa, minok, out);
    head_and_check<<<B_DIM, 512, 0, stream>>>(tokens, fsa, minok, need_fb, out);
    fallback_scan<<<B_DIM, NT, 0, stream>>>(tokens, fsa, need_fb, out);
}

// Round 4
// 22.279 us; speedup vs baseline: 32.1424x; 1.1885x over previous
//
#include <hip/hip_runtime.h>

// BRNN integrate one-hot: h_t = clip(h_{t-1} @ fsa[tok_t], -10, 10)
// B=64 L=512 S=128 V=10000, fsa = U[0,1) (non-negative by problem spec).
//
// clip(+10) is absorbing: h2 saturates to all-10s; it stays there for every
// token whose matrix has min column-sum >= 1. fsa >= 0, so a PARTIAL column
// sum over rows 0..12 >= 1 soundly lower-bounds the full column sum.
// (P(Irwin-Hall_13 < 1) = 1/13! ~ 1.6e-10; x 1.28M columns => ~2e-4 chance of
//  a spurious fallback — and fallback is exact anyway.)
//
//   k1 certify_fill_head : blocks 0..9999  = partial-colsum cert + 10.0-fill
//                          blocks 10000+   = exact t=0,1 head per batch (no minok dep)
//   k2 check_and_scan    : per-batch certificate check; exact full scan if failed

constexpr int S_DIM = 128;
constexpr int L_DIM = 512;
constexpr int B_DIM = 64;
constexpr int V_DIM = 10000;
constexpr int CR    = 13;         // certificate rows read per vocab matrix
constexpr int NT    = 512;
constexpr int RG    = NT / 32;
constexpr int RPG   = S_DIM / RG;

// ---------------- k1: cert + fill + head, one grid ----------------
__global__ __launch_bounds__(512)
void certify_fill_head(const float* __restrict__ fsa, const int* __restrict__ tokens,
                       int* __restrict__ minok, int* __restrict__ head_fail,
                       float* __restrict__ out) {
    const int tid = threadIdx.x;
    __shared__ float4 cpart[CR][32];
    __shared__ float  h1[S_DIM];
    __shared__ float  hpart[4][S_DIM];
    __shared__ int    flag;
    if (tid == 0) flag = 1;

    if (blockIdx.x < V_DIM) {
        const int v = blockIdx.x;

        // unconditional saturated fill: out[:, 2:, :] = 10.0 (blocks 0..2039)
        {
            const int per_b = (L_DIM - 2) * S_DIM / 4;          // 16320
            const int i = v * 512 + tid;
            if (i < per_b * B_DIM) {
                const int bb = i / per_b;
                const int r  = i - bb * per_b;
                float4* p = reinterpret_cast<float4*>(out + (size_t)bb * (L_DIM * S_DIM) + 2 * S_DIM);
                p[r] = make_float4(10.f, 10.f, 10.f, 10.f);
            }
        }

        // partial column sums over rows 0..CR-1
        const float* M = fsa + (size_t)v * (S_DIM * S_DIM);
        if (tid < CR * 32) {
            const int rg = tid >> 5;
            const int c4 = tid & 31;
            cpart[rg][c4] = *reinterpret_cast<const float4*>(M + rg * S_DIM + c4 * 4);
        }
        __syncthreads();
        if (tid < 32) {
            float4 s = cpart[0][tid];
            #pragma unroll
            for (int g = 1; g < CR; ++g) {
                float4 p = cpart[g][tid];
                s.x += p.x; s.y += p.y; s.z += p.z; s.w += p.w;
            }
            float mn = fminf(fminf(s.x, s.y), fminf(s.z, s.w));
            if (mn < 1.0f) flag = 0;       // only-zero writes: benign race
        }
        __syncthreads();
        if (tid == 0) minok[v] = flag;
    } else {
        // ---- head: exact t=0,1 for batch b ----
        const int b = blockIdx.x - V_DIM;
        const int j = tid & 127;
        const int q = tid >> 7;
        const int* btok = tokens + b * L_DIM;
        float* bout = out + (size_t)b * (L_DIM * S_DIM);

        const float* M0 = fsa + (size_t)btok[0] * (S_DIM * S_DIM);
        const float* M1 = fsa + (size_t)btok[1] * (S_DIM * S_DIM);

        if (q == 0) {
            float v0 = fminf(fmaxf(M0[j], -10.f), 10.f);
            h1[j] = v0;
            bout[j] = v0;
        }
        __syncthreads();

        float acc = 0.f;
        {
            const int s0 = q * 32;
            #pragma unroll 8
            for (int s = s0; s < s0 + 32; ++s)
                acc += h1[s] * M1[s * S_DIM + j];
        }
        hpart[q][j] = acc;
        __syncthreads();

        if (q == 0) {
            float v1 = hpart[0][j] + hpart[1][j] + hpart[2][j] + hpart[3][j];
            if (!(v1 >= 10.0f)) flag = 0;  // saturation must hold in every lane
            bout[S_DIM + j] = fminf(fmaxf(v1, -10.f), 10.f);
        }
        __syncthreads();
        if (tid == 0) head_fail[b] = !flag;
    }
}

// ---------------- k2: certificate check + gated exact scan ----------------
__global__ __launch_bounds__(NT, 2)
void check_and_scan(const int* __restrict__ tokens, const float* __restrict__ fsa,
                    const int* __restrict__ minok, const int* __restrict__ head_fail,
                    float* __restrict__ out) {
    const int b   = blockIdx.x;
    const int tid = threadIdx.x;
    const int* btok = tokens + b * L_DIM;

    __shared__ int sat;
    if (tid == 0) sat = head_fail[b] ? 0 : 1;
    __syncthreads();
    {
        const int t = 2 + tid;
        if (t < L_DIM && !minok[btok[t]]) sat = 0;
    }
    __syncthreads();
    if (sat) return;                       // certificate held: output already exact

    // ---- exact full scan for this batch (round-1 kernel body) ----
    const int cgrp = tid & 31;
    const int rgrp = tid >> 5;

    __shared__ float  h[S_DIM];
    __shared__ float4 part4[RG][32];

    if (tid < S_DIM) h[tid] = (tid == 0) ? 1.0f : 0.0f;

    float* bout = out + (size_t)b * (L_DIM * S_DIM);

    float4 cur[RPG];
    {
        const float* M = fsa + (size_t)btok[0] * (S_DIM * S_DIM);
        #pragma unroll
        for (int i = 0; i < RPG; ++i)
            cur[i] = *reinterpret_cast<const float4*>(M + (rgrp * RPG + i) * S_DIM + cgrp * 4);
    }
    __syncthreads();

    for (int t = 0; t < L_DIM; ++t) {
        const int tn = (t + 1 < L_DIM) ? (t + 1) : t;
        float4 nxt[RPG];
        {
            const float* M = fsa + (size_t)btok[tn] * (S_DIM * S_DIM);
            #pragma unroll
            for (int i = 0; i < RPG; ++i)
                nxt[i] = *reinterpret_cast<const float4*>(M + (rgrp * RPG + i) * S_DIM + cgrp * 4);
        }

        float4 acc = make_float4(0.f, 0.f, 0.f, 0.f);
        #pragma unroll
        for (int i = 0; i < RPG; ++i) {
            const float hs = h[rgrp * RPG + i];
            acc.x += hs * cur[i].x;
            acc.y += hs * cur[i].y;
            acc.z += hs * cur[i].z;
            acc.w += hs * cur[i].w;
        }

        __syncthreads();
        part4[rgrp][cgrp] = acc;
        __syncthreads();

        if (tid < S_DIM) {
            const float* pf = reinterpret_cast<const float*>(part4);
            float v = 0.f;
            #pragma unroll
            for (int g = 0; g < RG; ++g) v += pf[g * S_DIM + tid];
            v = fminf(fmaxf(v, -10.0f), 10.0f);
            bout[t * S_DIM + tid] = v;
            h[tid] = v;
        }
        __syncthreads();

        #pragma unroll
        for (int i = 0; i < RPG; ++i) cur[i] = nxt[i];
    }
}

extern "C" void kernel_launch(void* const* d_in, const int* in_sizes, int n_in,
                              void* d_out, int out_size, void* d_ws, size_t ws_size,
                              hipStream_t stream) {
    const int*   tokens = (const int*)d_in[0];     // [B, L]
    // d_in[1] = lengths — unused by the reference computation
    const float* fsa    = (const float*)d_in[2];   // [V, S, S] f32
    float*       out    = (float*)d_out;           // [B, L, S] f32

    int* minok     = (int*)d_ws;                   // [V_DIM]
    int* head_fail = minok + V_DIM;                // [B_DIM]

    certify_fill_head<<<V_DIM + B_DIM, 512, 0, stream>>>(fsa, tokens, minok, head_fail, out);
    check_and_scan<<<B_DIM, NT, 0, stream>>>(tokens, fsa, minok, head_fail, out);
}

// Round 5
// 19.398 us; speedup vs baseline: 36.9164x; 1.1485x over previous
//
#include <hip/hip_runtime.h>

// BRNN integrate one-hot: h_t = clip(h_{t-1} @ fsa[tok_t], -10, 10)
// B=64 L=512 S=128 V=10000, fsa = U[0,1) (non-negative by problem spec).
//
// clip(+10) is absorbing: h2 saturates to all-10s; it stays there for every
// token whose matrix has min column-sum >= 1. fsa >= 0, so a PARTIAL column
// sum >= 1 soundly lower-bounds the full column sum. Two-stage adaptive cert:
//   stage 1: rows 0..6   (P[col fails] = 1/7! => ~2.5% of matrices escalate)
//   stage 2: rows 7..12  (full 13-row bound; global false-trigger ~2e-4,
//                         and the fallback is exact anyway)
//
//   k1 certify_fill_head : blocks 0..9999  = adaptive cert + 10.0-fill of out[:,2:,:]
//                          blocks 10000+   = exact t=0,1 head per batch
//   k2 check_and_scan    : per-batch certificate check; exact full scan if failed

constexpr int S_DIM = 128;
constexpr int L_DIM = 512;
constexpr int B_DIM = 64;
constexpr int V_DIM = 10000;
constexpr int CR1   = 7;          // stage-1 certificate rows
constexpr int CR2   = 13;         // total rows after escalation
constexpr int NT    = 512;
constexpr int RG    = NT / 32;
constexpr int RPG   = S_DIM / RG;

// ---------------- k1: cert + fill + head, one grid ----------------
__global__ __launch_bounds__(512)
void certify_fill_head(const float* __restrict__ fsa, const int* __restrict__ tokens,
                       int* __restrict__ minok, int* __restrict__ head_fail,
                       float* __restrict__ out) {
    const int tid = threadIdx.x;
    __shared__ float4 cpart[CR2][32];
    __shared__ float  h1[S_DIM];
    __shared__ float  hpart[4][S_DIM];
    __shared__ int    esc, bad, flag;

    if (blockIdx.x < V_DIM) {
        const int v = blockIdx.x;
        if (tid == 0) { esc = 0; bad = 0; }

        // unconditional saturated fill: out[:, 2:, :] = 10.0 (blocks 0..2039)
        {
            const int per_b = (L_DIM - 2) * S_DIM / 4;          // 16320
            const int i = v * 512 + tid;
            if (i < per_b * B_DIM) {
                const int bb = i / per_b;
                const int r  = i - bb * per_b;
                float4* p = reinterpret_cast<float4*>(out + (size_t)bb * (L_DIM * S_DIM) + 2 * S_DIM);
                p[r] = make_float4(10.f, 10.f, 10.f, 10.f);
            }
        }

        const float* M = fsa + (size_t)v * (S_DIM * S_DIM);

        // stage 1: rows 0..CR1-1
        if (tid < CR1 * 32) {
            const int rg = tid >> 5;
            const int c4 = tid & 31;
            cpart[rg][c4] = *reinterpret_cast<const float4*>(M + rg * S_DIM + c4 * 4);
        }
        __syncthreads();

        float4 s;                            // live in tid<32 only
        if (tid < 32) {
            s = cpart[0][tid];
            #pragma unroll
            for (int g = 1; g < CR1; ++g) {
                float4 p = cpart[g][tid];
                s.x += p.x; s.y += p.y; s.z += p.z; s.w += p.w;
            }
            float mn = fminf(fminf(s.x, s.y), fminf(s.z, s.w));
            if (mn < 1.0f) esc = 1;          // set-to-1 race: benign
        }
        __syncthreads();

        if (esc) {                           // block-uniform branch
            // stage 2: rows CR1..CR2-1
            if (tid < (CR2 - CR1) * 32) {
                const int rg = CR1 + (tid >> 5);
                const int c4 = tid & 31;
                cpart[rg][c4] = *reinterpret_cast<const float4*>(M + rg * S_DIM + c4 * 4);
            }
            __syncthreads();
            if (tid < 32) {
                #pragma unroll
                for (int g = CR1; g < CR2; ++g) {
                    float4 p = cpart[g][tid];
                    s.x += p.x; s.y += p.y; s.z += p.z; s.w += p.w;
                }
                float mn = fminf(fminf(s.x, s.y), fminf(s.z, s.w));
                if (mn < 1.0f) bad = 1;      // set-to-1 race: benign
            }
            __syncthreads();
        }
        if (tid == 0) minok[v] = !bad;
    } else {
        // ---- head: exact t=0,1 for batch b ----
        const int b = blockIdx.x - V_DIM;
        const int j = tid & 127;
        const int q = tid >> 7;
        const int* btok = tokens + b * L_DIM;
        float* bout = out + (size_t)b * (L_DIM * S_DIM);

        if (tid == 0) flag = 1;

        const float* M0 = fsa + (size_t)btok[0] * (S_DIM * S_DIM);
        const float* M1 = fsa + (size_t)btok[1] * (S_DIM * S_DIM);

        if (q == 0) {
            float v0 = fminf(fmaxf(M0[j], -10.f), 10.f);
            h1[j] = v0;
            bout[j] = v0;
        }
        __syncthreads();

        float acc = 0.f;
        {
            const int s0 = q * 32;
            #pragma unroll 8
            for (int s2 = s0; s2 < s0 + 32; ++s2)
                acc += h1[s2] * M1[s2 * S_DIM + j];
        }
        hpart[q][j] = acc;
        __syncthreads();

        if (q == 0) {
            float v1 = hpart[0][j] + hpart[1][j] + hpart[2][j] + hpart[3][j];
            if (!(v1 >= 10.0f)) flag = 0;    // saturation must hold in every lane
            bout[S_DIM + j] = fminf(fmaxf(v1, -10.f), 10.f);
        }
        __syncthreads();
        if (tid == 0) head_fail[b] = !flag;
    }
}

// ---------------- k2: certificate check + gated exact scan ----------------
__global__ __launch_bounds__(NT, 2)
void check_and_scan(const int* __restrict__ tokens, const float* __restrict__ fsa,
                    const int* __restrict__ minok, const int* __restrict__ head_fail,
                    float* __restrict__ out) {
    const int b   = blockIdx.x;
    const int tid = threadIdx.x;
    const int* btok = tokens + b * L_DIM;

    __shared__ int sat;
    if (tid == 0) sat = head_fail[b] ? 0 : 1;
    __syncthreads();
    {
        const int t = 2 + tid;
        if (t < L_DIM && !minok[btok[t]]) sat = 0;
    }
    __syncthreads();
    if (sat) return;                       // certificate held: output already exact

    // ---- exact full scan for this batch (round-1 kernel body) ----
    const int cgrp = tid & 31;
    const int rgrp = tid >> 5;

    __shared__ float  h[S_DIM];
    __shared__ float4 part4[RG][32];

    if (tid < S_DIM) h[tid] = (tid == 0) ? 1.0f : 0.0f;

    float* bout = out + (size_t)b * (L_DIM * S_DIM);

    float4 cur[RPG];
    {
        const float* M = fsa + (size_t)btok[0] * (S_DIM * S_DIM);
        #pragma unroll
        for (int i = 0; i < RPG; ++i)
            cur[i] = *reinterpret_cast<const float4*>(M + (rgrp * RPG + i) * S_DIM + cgrp * 4);
    }
    __syncthreads();

    for (int t = 0; t < L_DIM; ++t) {
        const int tn = (t + 1 < L_DIM) ? (t + 1) : t;
        float4 nxt[RPG];
        {
            const float* M = fsa + (size_t)btok[tn] * (S_DIM * S_DIM);
            #pragma unroll
            for (int i = 0; i < RPG; ++i)
                nxt[i] = *reinterpret_cast<const float4*>(M + (rgrp * RPG + i) * S_DIM + cgrp * 4);
        }

        float4 acc = make_float4(0.f, 0.f, 0.f, 0.f);
        #pragma unroll
        for (int i = 0; i < RPG; ++i) {
            const float hs = h[rgrp * RPG + i];
            acc.x += hs * cur[i].x;
            acc.y += hs * cur[i].y;
            acc.z += hs * cur[i].z;
            acc.w += hs * cur[i].w;
        }

        __syncthreads();
        part4[rgrp][cgrp] = acc;
        __syncthreads();

        if (tid < S_DIM) {
            const float* pf = reinterpret_cast<const float*>(part4);
            float v = 0.f;
            #pragma unroll
            for (int g = 0; g < RG; ++g) v += pf[g * S_DIM + tid];
            v = fminf(fmaxf(v, -10.0f), 10.0f);
            bout[t * S_DIM + tid] = v;
            h[tid] = v;
        }
        __syncthreads();

        #pragma unroll
        for (int i = 0; i < RPG; ++i) cur[i] = nxt[i];
    }
}

extern "C" void kernel_launch(void* const* d_in, const int* in_sizes, int n_in,
                              void* d_out, int out_size, void* d_ws, size_t ws_size,
                              hipStream_t stream) {
    const int*   tokens = (const int*)d_in[0];     // [B, L]
    // d_in[1] = lengths — unused by the reference computation
    const float* fsa    = (const float*)d_in[2];   // [V, S, S] f32
    float*       out    = (float*)d_out;           // [B, L, S] f32

    int* minok     = (int*)d_ws;                   // [V_DIM]
    int* head_fail = minok + V_DIM;                // [B_DIM]

    certify_fill_head<<<V_DIM + B_DIM, 512, 0, stream>>>(fsa, tokens, minok, head_fail, out);
    check_and_scan<<<B_DIM, NT, 0, stream>>>(tokens, fsa, minok, head_fail, out);
}